// Round 2
// baseline (397.574 us; speedup 1.0000x reference)
//
#include <hip/hip_runtime.h>

// Lukasiewicz t-norm feature expansion.
//   out[:, 0:16]    = x
//   out[:, 16:136]  = max(x[a]+x[b] - 1, 0)          (a,b)   lex combos of 16
//   out[:, 136:696] = max((x[a]+x[b]) + x[c] - 2, 0) (a,b,c) lex combos of 16
//
// R4 = R3 structure with PLAIN stores instead of __builtin_nontemporal_store.
// Evidence: kernel effective write BW with NT float4 stores ~2.5 TB/s vs the
// harness fill's 6.3 TB/s on the same buffer; prior session saw BW scale ~4x
// with per-lane NT store width (dword 0.78 -> float4 2.7 TB/s), the signature
// of NT bypassing L2 write-combining (each store its own partial transaction).
// Plain stores let L2 merge lanes + phase-boundary segments into full lines.

#define NCOLS 696
#define RPT   16          // rows per tile
#define RSTR  140         // per-row LDS floats: [0..15]=x, [16..135]=raw pair sums, pad 4
#define PQ    30          // pair quads per row   (120/4)
#define TQ    140         // triple quads per row (560/4)

typedef float v4f __attribute__((ext_vector_type(4)));

struct alignas(16) TripTab { unsigned short v[560]; };
struct alignas(16) PairTab { unsigned short v[120]; };

// triple descriptor: (16 + pairIdx(a,b)) in bits [7:0], c in bits [11:8]
constexpr TripTab make_ttab() {
    TripTab t{};
    int pidx[16][16] = {};
    int pi = 0;
    for (int a = 0; a < 16; ++a)
        for (int b = a + 1; b < 16; ++b)
            pidx[a][b] = pi++;
    int k = 0;
    for (int a = 0; a < 16; ++a)
        for (int b = a + 1; b < 16; ++b)
            for (int c = b + 1; c < 16; ++c)
                t.v[k++] = (unsigned short)((16 + pidx[a][b]) | (c << 8));
    return t;
}
// pair descriptor: a in [4:0], b in [9:5], lex order
constexpr PairTab make_ptab() {
    PairTab t{};
    int k = 0;
    for (int a = 0; a < 16; ++a)
        for (int b = a + 1; b < 16; ++b)
            t.v[k++] = (unsigned short)(a | (b << 5));
    return t;
}

__constant__ TripTab g_ttab = make_ttab();
__constant__ PairTab g_ptab = make_ptab();

__global__ __launch_bounds__(256) void luk_kernel(const float* __restrict__ x,
                                                  float* __restrict__ out,
                                                  int nrows, int ntiles) {
    // 16 rows x 140 floats = 8960 B LDS; row stride 560 B is 16B-aligned so
    // pair-sum quads can be ds_write_b128 / ds_read_b128.
    __shared__ float L[RPT * RSTR];
    const int t = threadIdx.x;
    const ushort4* __restrict__ tt4 = reinterpret_cast<const ushort4*>(g_ttab.v);
    const ushort4* __restrict__ pt4 = reinterpret_cast<const ushort4*>(g_ptab.v);

    for (int tile = blockIdx.x; tile < ntiles; tile += gridDim.x) {
        const int row0 = tile * RPT;
        const int rlim = min(RPT, nrows - row0);
        const size_t obase = (size_t)row0 * NCOLS;

        {   // stage x: 256 consecutive floats, coalesced
            const int r = t >> 4, a = t & 15;
            float v = 0.0f;
            if (r < rlim) v = x[(size_t)row0 * 16 + t];
            L[r * RSTR + a] = v;
        }
        __syncthreads();

        // ---- phase A: pairs. Emit out[:,16..136) and stash raw sums in LDS.
        for (int i = t; i < rlim * PQ; i += 256) {
            const int r = (unsigned)i / (unsigned)PQ;
            const int q = i - r * PQ;
            const ushort4 pv = pt4[q];
            const float* __restrict__ xr = &L[r * RSTR];
            const float s0 = xr[pv.x & 31] + xr[pv.x >> 5];
            const float s1 = xr[pv.y & 31] + xr[pv.y >> 5];
            const float s2 = xr[pv.z & 31] + xr[pv.z >> 5];
            const float s3 = xr[pv.w & 31] + xr[pv.w >> 5];
            v4f sv; sv.x = s0; sv.y = s1; sv.z = s2; sv.w = s3;
            *reinterpret_cast<v4f*>(&L[r * RSTR + 16 + 4 * q]) = sv;  // raw sums
            v4f o;
            o.x = fmaxf(s0 - 1.0f, 0.0f);
            o.y = fmaxf(s1 - 1.0f, 0.0f);
            o.z = fmaxf(s2 - 1.0f, 0.0f);
            o.w = fmaxf(s3 - 1.0f, 0.0f);
            reinterpret_cast<v4f*>(out + obase + (size_t)r * NCOLS + 16)[q] = o;
        }

        // ---- phase B: singles. out[:,0..16) = x (64 quads).
        if (t < rlim * 4) {
            const int r = t >> 2, q = t & 3;
            const v4f o = *reinterpret_cast<const v4f*>(&L[r * RSTR + 4 * q]);
            reinterpret_cast<v4f*>(out + obase + (size_t)r * NCOLS)[q] = o;
        }
        __syncthreads();   // pair sums visible

        // ---- phase C: triples. out[:,136..696) = max((ps + xc) - 2, 0).
        const int nq = rlim * TQ;
        for (int i = t; i < nq; i += 256) {
            const int r = (unsigned)i / (unsigned)TQ;
            const int q = i - r * TQ;
            const ushort4 tv = tt4[q];
            const float* __restrict__ xr = &L[r * RSTR];
            v4f o;
            o.x = fmaxf(xr[tv.x & 255] + xr[tv.x >> 8] - 2.0f, 0.0f);
            o.y = fmaxf(xr[tv.y & 255] + xr[tv.y >> 8] - 2.0f, 0.0f);
            o.z = fmaxf(xr[tv.z & 255] + xr[tv.z >> 8] - 2.0f, 0.0f);
            o.w = fmaxf(xr[tv.w & 255] + xr[tv.w >> 8] - 2.0f, 0.0f);
            reinterpret_cast<v4f*>(out + obase + (size_t)r * NCOLS + 136)[q] = o;
        }
        __syncthreads();   // L reused next tile
    }
}

extern "C" void kernel_launch(void* const* d_in, const int* in_sizes, int n_in,
                              void* d_out, int out_size, void* d_ws, size_t ws_size,
                              hipStream_t stream) {
    const float* x = (const float*)d_in[0];
    float* out = (float*)d_out;
    const int nrows  = in_sizes[0] / 16;            // 131072
    const int ntiles = (nrows + RPT - 1) / RPT;     // 8192
    const int blocks = ntiles < 2048 ? ntiles : 2048;  // 8 blocks/CU resident
    luk_kernel<<<blocks, 256, 0, stream>>>(x, out, nrows, ntiles);
}

// Round 3
// 372.853 us; speedup vs baseline: 1.0663x; 1.0663x over previous
//
#include <hip/hip_runtime.h>

// Lukasiewicz t-norm feature expansion.
//   out[:, 0:16]    = x
//   out[:, 16:136]  = max(x[a]+x[b] - 1, 0)        (a,b)   lex combos of 16
//   out[:, 136:696] = max(x[a]+x[b]+x[c] - 2, 0)   (a,b,c) lex combos of 16
//
// R5 = R2's structure (fused single loop, LINEAR quad->lane store pattern:
// every wave-store covers 8 full 128B-aligned lines, tile base 44544 B = 348
// lines exactly) with PLAIN stores instead of nontemporal.
// Evidence matrix: R2 NT+aligned ~135us kernel; R3 NT+misaligned ~162; R4
// plain+misaligned ~152. NT width-scaling (dword 0.78 -> dwordx4 2.7 TB/s,
// ~4x) says NT stores hit HBM as store-width transactions, never line-merged.
// Plain stores merge in L2 (the 1.46GB harness fill sustains 6.3 TB/s with
// them). plain+aligned is the untested cell -> expect fill-like drain.

#define NCOLS 696
#define NC4   174          // NCOLS / 4
#define RPT   16           // rows per tile
#define QPT   (RPT * NC4)  // 2784 quads per tile, linear in memory

typedef float v4f __attribute__((ext_vector_type(4)));

struct ColTab { unsigned int v[NCOLS]; };

// Packed per-column descriptor: a[4:0] | b[9:5] | c[14:10] | bias[16:15]
// index 16 -> zero slot. Order matches itertools.combinations (lex).
constexpr ColTab make_tab() {
    ColTab t{};
    int k = 0;
    for (int a = 0; a < 16; ++a)
        t.v[k++] = (unsigned)a | (16u << 5) | (16u << 10);
    for (int a = 0; a < 16; ++a)
        for (int b = a + 1; b < 16; ++b)
            t.v[k++] = (unsigned)a | ((unsigned)b << 5) | (16u << 10) | (1u << 15);
    for (int a = 0; a < 16; ++a)
        for (int b = a + 1; b < 16; ++b)
            for (int c = b + 1; c < 16; ++c)
                t.v[k++] = (unsigned)a | ((unsigned)b << 5) | ((unsigned)c << 10) | (2u << 15);
    return t;
}

__constant__ ColTab g_tab = make_tab();

__device__ __forceinline__ float tnorm(const float* __restrict__ xr, unsigned v) {
    return fmaxf(xr[v & 31u] + xr[(v >> 5) & 31u] + xr[(v >> 10) & 31u]
                 - (float)((v >> 15) & 3u), 0.0f);
}

__global__ __launch_bounds__(256) void luk_kernel(const float* __restrict__ x,
                                                  float* __restrict__ out,
                                                  int nrows, int ntiles) {
    // 16 rows * (16 vals + zero slot), stride 17: intra-row reads hit 17
    // distinct banks (same-addr broadcasts free); cross-row aliasing <=2-way.
    __shared__ float xl[RPT * 17];
    const int t = threadIdx.x;
    const uint4* __restrict__ tab4 = reinterpret_cast<const uint4*>(g_tab.v);
    v4f* __restrict__ out4 = reinterpret_cast<v4f*>(out);

    for (int tile = blockIdx.x; tile < ntiles; tile += gridDim.x) {
        const int row0 = tile * RPT;
        const int rlim = min(RPT, nrows - row0);

        {   // cooperative coalesced load: 256 consecutive floats
            const int r = t >> 4, a = t & 15;
            float v = 0.0f;
            if (r < rlim) v = x[(size_t)row0 * 16 + t];
            xl[r * 17 + a] = v;
            if (t < RPT) xl[t * 17 + 16] = 0.0f;
        }
        __syncthreads();

        // Linear quad index i: store address = out + tile*44544B + 16B*i.
        // Consecutive lanes -> consecutive 16B quads -> each wave-store is
        // 1024B covering 8 full, 128B-aligned lines (tile base is line-
        // aligned): plain stores fully merge, no partial-line traffic.
        const int nq = rlim * NC4;
        const size_t qbase = (size_t)row0 * NC4;
        for (int i = t; i < nq; i += 256) {
            const int r  = (unsigned)i / (unsigned)NC4;
            const int c4 = i - r * NC4;
            const uint4 tv = tab4[c4];
            const float* __restrict__ xr = &xl[r * 17];
            v4f o;
            o.x = tnorm(xr, tv.x);
            o.y = tnorm(xr, tv.y);
            o.z = tnorm(xr, tv.z);
            o.w = tnorm(xr, tv.w);
            out4[qbase + i] = o;
        }
        __syncthreads();   // xl reused next tile
    }
}

extern "C" void kernel_launch(void* const* d_in, const int* in_sizes, int n_in,
                              void* d_out, int out_size, void* d_ws, size_t ws_size,
                              hipStream_t stream) {
    const float* x = (const float*)d_in[0];
    float* out = (float*)d_out;
    const int nrows  = in_sizes[0] / 16;           // 131072
    const int ntiles = (nrows + RPT - 1) / RPT;    // 8192
    const int blocks = ntiles < 2048 ? ntiles : 2048;  // 8 blocks/CU resident
    luk_kernel<<<blocks, 256, 0, stream>>>(x, out, nrows, ntiles);
}